// Round 8
// baseline (231.152 us; speedup 1.0000x reference)
//
#include <hip/hip_runtime.h>
#include <hip/hip_bf16.h>

typedef unsigned short u16;
typedef unsigned int u32;
typedef __attribute__((ext_vector_type(8))) short short8;   // 8 x bf16 frag
typedef __attribute__((ext_vector_type(4))) short short4v;  // 4 x bf16 pack
typedef __attribute__((ext_vector_type(16))) float f32x16;  // 32x32 acc

#define MFMA32 __builtin_amdgcn_mfma_f32_32x32x16_bf16

#define NSEQ 4096
#define CD 256
// (1/sqrt(256)) * log2(e) = 0.0625 * 1.4426950408889634  -- EXACT.
#define CF 0.09016844005556021f

__device__ __forceinline__ u16 f2bf(float f) {
  u32 u = __float_as_uint(f);
  u += 0x7fffu + ((u >> 16) & 1u);  // RNE
  return (u16)(u >> 16);
}
__device__ __forceinline__ float bf2f(short s) {
  return __uint_as_float(((u32)(u16)s) << 16);
}
// HW packed f32x2 -> bf16x2 (gfx950 v_cvt_pk_bf16_f32), RNE
__device__ __forceinline__ u32 pk2bf(float a, float b) {
  union {
    __hip_bfloat162 h;
    u32 u;
  } cv;
  cv.h = __float22bfloat162_rn(make_float2(a, b));
  return cv.u;
}
// async global -> LDS DMA, 16B per lane; LDS dest = wave-uniform base + lane*16
__device__ __forceinline__ void async16(const void* g, void* l) {
  __builtin_amdgcn_global_load_lds(
      (const __attribute__((address_space(1))) u32*)g,
      (__attribute__((address_space(3))) u32*)l, 16, 0, 0);
}

// ---------------------------------------------------------------------------
// cast weights fp32 -> bf16
// ---------------------------------------------------------------------------
__global__ void cast_w(const float* __restrict__ qkv_w,
                       const float* __restrict__ out_w, u16* __restrict__ wq,
                       u16* __restrict__ wo) {
  int idx = blockIdx.x * 256 + threadIdx.x;
  if (idx < 768 * CD) wq[idx] = f2bf(qkv_w[idx]);
  if (idx < CD * CD) wo[idx] = f2bf(out_w[idx]);
}

// ---------------------------------------------------------------------------
// transpose-cast x: (b, 256, 4096) f32 -> x_t (b, 4096, 256) bf16
// ---------------------------------------------------------------------------
__global__ __launch_bounds__(256) void xpose(const float* __restrict__ x,
                                             u16* __restrict__ x_t) {
  __shared__ float tile[64][65];
  const int t = threadIdx.x;
  const int b = blockIdx.z;
  const int n0 = blockIdx.x * 64, c0 = blockIdx.y * 64;
  const float* xb = x + (size_t)b * CD * NSEQ;
  const int cr = t >> 4, nc4 = (t & 15) * 4;
#pragma unroll
  for (int i = 0; i < 4; ++i) {
    int c = cr + 16 * i;
    float4 v = *(const float4*)(xb + (size_t)(c0 + c) * NSEQ + n0 + nc4);
    tile[c][nc4 + 0] = v.x;
    tile[c][nc4 + 1] = v.y;
    tile[c][nc4 + 2] = v.z;
    tile[c][nc4 + 3] = v.w;
  }
  __syncthreads();
  const int n = t & 63, cc = (t >> 6) * 16;
  u16* dst = x_t + (size_t)b * NSEQ * CD + (size_t)(n0 + n) * CD + c0 + cc;
#pragma unroll
  for (int j = 0; j < 4; ++j) {
    short4v pv;
#pragma unroll
    for (int r = 0; r < 4; ++r) pv[r] = (short)f2bf(tile[cc + 4 * j + r][n]);
    *(short4v*)(dst + 4 * j) = pv;
  }
}

// ---------------------------------------------------------------------------
// QKV projection, 128x128 tile, 512 threads (8 waves), 32x32x16 MFMA.
// Wave w: o-strip (w&3)*32, n-half (w>>2)*64 (2 accs of 32n each).
// grid (32, 6, 4): blockIdx.y in {0,1}=Q {2,3}=K {4,5}=V (128 | 256).
// ---------------------------------------------------------------------------
__global__ __launch_bounds__(512, 1) void qkv_gemm3(
    const u16* __restrict__ wq, const float* __restrict__ qkv_b,
    const u16* __restrict__ x_t, u16* __restrict__ q_t, u16* __restrict__ k_t,
    u16* __restrict__ v_) {
  __shared__ u16 __align__(16) Wls[128 * 256];
  __shared__ u16 __align__(16) Bls[128 * 256];
  const int t = threadIdx.x, w = t >> 6, lane = t & 63;
  const int l31 = lane & 31, l5 = lane >> 5;
  const int os = w & 3, nh = w >> 2;
  const int n0 = blockIdx.x * 128, o0 = blockIdx.y * 128, b = blockIdx.z;
  const u16* Xb = x_t + (size_t)b * NSEQ * CD;
#pragma unroll
  for (int j = 0; j < 8; ++j) {
    int r = w * 16 + j * 2 + l5;
    async16(wq + (size_t)(o0 + r) * CD + ((l31 ^ (r & 7)) * 8),
            Wls + (w * 16 + j * 2) * 256);
    async16(Xb + (size_t)(n0 + r) * CD + ((l31 ^ (r & 7)) * 8),
            Bls + (w * 16 + j * 2) * 256);
  }
  __builtin_amdgcn_s_waitcnt(0);
  __syncthreads();
  f32x16 acc0, acc1;
#pragma unroll
  for (int i = 0; i < 16; ++i) {
    acc0[i] = 0.f;
    acc1[i] = 0.f;
  }
  const int ra = os * 32 + l31;
  const int rb0 = nh * 64 + l31, rb1 = rb0 + 32;
#pragma unroll
  for (int kc = 0; kc < 16; ++kc) {
    short8 a = *(const short8*)(Wls + ra * 256 + (((kc * 2 + l5) ^ (ra & 7)) * 8));
    short8 b0 = *(const short8*)(Bls + rb0 * 256 + (((kc * 2 + l5) ^ (rb0 & 7)) * 8));
    short8 b1 = *(const short8*)(Bls + rb1 * 256 + (((kc * 2 + l5) ^ (rb1 & 7)) * 8));
    acc0 = MFMA32(a, b0, acc0, 0, 0, 0);
    acc1 = MFMA32(a, b1, acc1, 0, 0, 0);
  }
  const int otype = blockIdx.y >> 1;  // 0=Q 1=K 2=V
  const int obase = o0 + os * 32;
#pragma unroll
  for (int na = 0; na < 2; ++na) {
    f32x16& acc = na ? acc1 : acc0;
    const int n_g = n0 + nh * 64 + na * 32 + l31;
    if (otype < 2) {
      u16* dst = (otype == 0 ? q_t : k_t) + (size_t)b * NSEQ * CD +
                 (size_t)n_g * CD + (obase - otype * 256);
#pragma unroll
      for (int g = 0; g < 4; ++g) {
        float4 bv = *(const float4*)(qkv_b + obase + g * 8 + l5 * 4);
        const float* bp = (const float*)&bv;
        short4v pk;
#pragma unroll
        for (int r = 0; r < 4; ++r) pk[r] = (short)f2bf(acc[g * 4 + r] + bp[r]);
        *(short4v*)(dst + g * 8 + l5 * 4) = pk;
      }
    } else {
      u16* dst = v_ + (size_t)b * CD * NSEQ;
#pragma unroll
      for (int g = 0; g < 4; ++g) {
        float4 bv = *(const float4*)(qkv_b + obase + g * 8 + l5 * 4);
        const float* bp = (const float*)&bv;
#pragma unroll
        for (int r = 0; r < 4; ++r) {
          int c = obase - 512 + g * 8 + l5 * 4 + r;
          dst[(size_t)c * NSEQ + n_g] = f2bf(acc[g * 4 + r] + bp[r]);
        }
      }
    }
  }
}

// ---------------------------------------------------------------------------
// Flash attention v6: barrier-minimal. 512 threads (8 waves), m-tile 128,
// key-split 2, double-buffered K/V DMA (128 KB LDS, nothing else).
// Wave w: m-strip s = w>>1 (32 m), c-half ch = (w&1)*128.
//   S : FULL 64n x own 32m (2 accs, 32 MFMA) -- duplicated by the c-half pair.
//   softmax: per-lane + one shfl_xor(32). No LDS, no barriers.
//   P : C/D-layout -> B-operand layout via 8 shfl_xor(32) on packed bf16
//       dwords (l5-partner exchange). No LDS.
//   PV: own c-half 128 x own 32m (16 MFMA).
// ONE barrier per tile (dbuf drain). Emits per-half normalized O + (m,l).
// ---------------------------------------------------------------------------
__global__ __launch_bounds__(512, 1) void flash6(const u16* __restrict__ q_t,
                                                 const u16* __restrict__ k_t,
                                                 const u16* __restrict__ v_,
                                                 u16* __restrict__ opart,
                                                 float2* __restrict__ ml) {
  __shared__ u16 __align__(16) Kls[2][64 * 256];  // [buf][n][c] swizzled
  __shared__ u16 __align__(16) Vls[2][256 * 64];  // [buf][c][n] swizzled

  const int t = threadIdx.x, w = t >> 6, lane = t & 63;
  const int l31 = lane & 31, l5 = lane >> 5;
  const int s = w >> 1, ch = (w & 1) * 128;

  // XCD swizzle: each XCD owns one (batch, key-half) -> 4MB K/V in its L2.
  const int linear = blockIdx.x;
  const int xcd = linear & 7, slot = linear >> 3;  // slot in [0,32)
  const int b = xcd >> 1, half = xcd & 1;
  const int m0 = slot * 128;
  const int nbase = half * 2048;

  const u16* Qb = q_t + (size_t)b * NSEQ * CD;
  const u16* Kb = k_t + (size_t)b * NSEQ * CD;
  const u16* Vb = v_ + (size_t)b * CD * NSEQ;

  const int lm = s * 32 + l31;  // m within the 128-tile
  const int mrow = m0 + lm;     // global query index

  // Q fragments in registers (B-operand for S), K=256
  short8 qf[16];
#pragma unroll
  for (int kc = 0; kc < 16; ++kc)
    qf[kc] = *(const short8*)(Qb + (size_t)mrow * CD + kc * 16 + l5 * 8);

  const int kr = w * 8;   // K staging rows (2/DMA, 4 DMA)
  const int vrb = w * 32; // V staging rows (8/DMA, 4 DMA)
  const int vr_lane = lane >> 3, vc_lane = lane & 7;

  // stage tile 0 into buf 0
#pragma unroll
  for (int j = 0; j < 4; ++j) {
    int r = kr + j * 2 + l5;
    async16(Kb + (size_t)(nbase + r) * CD + ((l31 ^ (r & 7)) * 8),
            &Kls[0][(kr + j * 2) * 256]);
    int rv = vrb + j * 8 + vr_lane;
    async16(Vb + (size_t)rv * NSEQ + nbase + ((vc_lane ^ (rv & 7)) * 8),
            &Vls[0][(vrb + j * 8) * 64]);
  }

  float mst = -3.0e38f, lst = 0.f;
  f32x16 oa[4];  // O[c = ch + ct*32 + rowmap][m = mrow]
#pragma unroll
  for (int i = 0; i < 4; ++i)
#pragma unroll
    for (int r = 0; r < 16; ++r) oa[i][r] = 0.f;

  for (int tt = 0; tt < 32; ++tt) {
    const int cur = tt & 1;
    // drain: tile tt's DMA complete; all waves done reading buf[cur] tile tt-2
    __builtin_amdgcn_s_waitcnt(0);
    __syncthreads();
    if (tt + 1 < 32) {
      const int n0 = nbase + (tt + 1) * 64;
      const int nxt = cur ^ 1;
#pragma unroll
      for (int j = 0; j < 4; ++j) {
        int r = kr + j * 2 + l5;
        async16(Kb + (size_t)(n0 + r) * CD + ((l31 ^ (r & 7)) * 8),
                &Kls[nxt][(kr + j * 2) * 256]);
        int rv = vrb + j * 8 + vr_lane;
        async16(Vb + (size_t)rv * NSEQ + n0 + ((vc_lane ^ (rv & 7)) * 8),
                &Vls[nxt][(vrb + j * 8) * 64]);
      }
    }
    // ---- S = K . Q^T : full 64n x own 32m (2 accs) ----
    f32x16 sa, sb;
#pragma unroll
    for (int i = 0; i < 16; ++i) {
      sa[i] = 0.f;
      sb[i] = 0.f;
    }
    const int rk0 = l31, rk1 = 32 + l31;  // (32+l31)&7 == l31&7
#pragma unroll
    for (int kc = 0; kc < 16; ++kc) {
      short8 a0 =
          *(const short8*)(&Kls[cur][rk0 * 256 + (((kc * 2 + l5) ^ (l31 & 7)) * 8)]);
      short8 a1 =
          *(const short8*)(&Kls[cur][rk1 * 256 + (((kc * 2 + l5) ^ (l31 & 7)) * 8)]);
      sa = MFMA32(a0, qf[kc], sa, 0, 0, 0);
      sb = MFMA32(a1, qf[kc], sb, 0, 0, 0);
    }
    // ---- softmax, fully in-wave (m = l31 per lane) ----
    float rm = sa[0];
#pragma unroll
    for (int i = 1; i < 16; ++i) rm = fmaxf(rm, sa[i]);
#pragma unroll
    for (int i = 0; i < 16; ++i) rm = fmaxf(rm, sb[i]);
    rm = fmaxf(rm, __shfl_xor(rm, 32));
    float mnew = fmaxf(mst, rm * CF);
    float al = exp2f(mst - mnew);
    mst = mnew;
    // p = exp2(s*CF - mnew); pack to bf16 dwords d[acc][gg][x]
    // (holds n = 32a + 8gg + 4*l5 + 2x + {0,1})
    u32 d[2][4][2];
    float ls = 0.f;
#pragma unroll
    for (int a = 0; a < 2; ++a) {
      f32x16& sv = a ? sb : sa;
#pragma unroll
      for (int gg = 0; gg < 4; ++gg) {
        float p0 = exp2f(sv[gg * 4 + 0] * CF - mnew);
        float p1 = exp2f(sv[gg * 4 + 1] * CF - mnew);
        float p2 = exp2f(sv[gg * 4 + 2] * CF - mnew);
        float p3 = exp2f(sv[gg * 4 + 3] * CF - mnew);
        ls += (p0 + p1) + (p2 + p3);
        d[a][gg][0] = pk2bf(p0, p1);
        d[a][gg][1] = pk2bf(p2, p3);
      }
    }
    ls += __shfl_xor(ls, 32);
    lst = lst * al + ls;
    // ---- rescale O only when the running max moved (rare) ----
    if (__ballot(al != 1.0f)) {
#pragma unroll
      for (int i = 0; i < 4; ++i)
#pragma unroll
        for (int r = 0; r < 16; ++r) oa[i][r] *= al;
    }
    // ---- build P B-frags via l5-partner exchange (8 shfl_xor) ----
    short8 pf[4];
#pragma unroll
    for (int f = 0; f < 4; ++f) {
      const int a = f >> 1, g0 = (f & 1) * 2;
      u32 n0d = d[a][g0][0], n1d = d[a][g0][1];
      u32 m0d = d[a][g0 + 1][0], m1d = d[a][g0 + 1][1];
      u32 s0 = l5 ? n0d : m0d;
      u32 s1 = l5 ? n1d : m1d;
      u32 e0 = (u32)__shfl_xor((int)s0, 32);
      u32 e1 = (u32)__shfl_xor((int)s1, 32);
      union {
        u32 u[4];
        short8 s8;
      } cv;
      cv.u[0] = l5 ? e0 : n0d;
      cv.u[1] = l5 ? e1 : n1d;
      cv.u[2] = l5 ? m0d : e0;
      cv.u[3] = l5 ? m1d : e1;
      pf[f] = cv.s8;
    }
    // ---- O += V . P : own c-half (4 subtiles) x own 32m ----
#pragma unroll
    for (int f = 0; f < 4; ++f) {
#pragma unroll
      for (int ct = 0; ct < 4; ++ct) {
        int c = ch + ct * 32 + l31;
        short8 vf =
            *(const short8*)(&Vls[cur][c * 64 + (((f * 2 + l5) ^ (c & 7)) * 8)]);
        oa[ct] = MFMA32(vf, pf[f], oa[ct], 0, 0, 0);
      }
    }
  }

  // ---- finalize: per-half normalized O -> bf16; (m,l) for merge ----
  float inv = 1.0f / lst;
  u16* dst = opart + ((size_t)(half * 4 + b) * NSEQ + mrow) * CD;
#pragma unroll
  for (int ct = 0; ct < 4; ++ct)
#pragma unroll
    for (int gg = 0; gg < 4; ++gg) {
      short4v pk;
#pragma unroll
      for (int r = 0; r < 4; ++r) pk[r] = (short)f2bf(oa[ct][gg * 4 + r] * inv);
      *(short4v*)(dst + ch + ct * 32 + gg * 8 + l5 * 4) = pk;
    }
  if ((w & 1) == 0 && lane < 32)
    ml[(size_t)(half * 4 + b) * NSEQ + m0 + s * 32 + lane] =
        make_float2(mst, lst);
}

// ---------------------------------------------------------------------------
// out projection + split-key merge folded into B-tile staging.
// 128n x 128o tiles, 512 threads. grid (32, 2, 4).
// ---------------------------------------------------------------------------
__global__ __launch_bounds__(512, 1) void out_gemm5(
    const u16* __restrict__ wo, const float* __restrict__ out_b,
    const u16* __restrict__ opart, const float2* __restrict__ ml,
    float* __restrict__ out) {
  __shared__ u16 __align__(16) Wls[128 * 256];
  __shared__ u16 __align__(16) Bls[128 * 256];
  const int t = threadIdx.x, w = t >> 6, lane = t & 63;
  const int l31 = lane & 31, l5 = lane >> 5;
  const int os = w & 3, nh = w >> 2;
  const int n0 = blockIdx.x * 128, o0 = blockIdx.y * 128, b = blockIdx.z;
#pragma unroll
  for (int j = 0; j < 8; ++j) {
    int r = w * 16 + j * 2 + l5;
    async16(wo + (size_t)(o0 + r) * CD + ((l31 ^ (r & 7)) * 8),
            Wls + (w * 16 + j * 2) * 256);
  }
  const u16* O1 = opart + (size_t)b * NSEQ * CD;
  const u16* O2 = opart + (size_t)(4 + b) * NSEQ * CD;
  const float2* ml1 = ml + (size_t)b * NSEQ;
  const float2* ml2 = ml + (size_t)(4 + b) * NSEQ;
#pragma unroll
  for (int i = 0; i < 8; ++i) {
    int idx = i * 512 + t;
    int r = idx >> 5, p = idx & 31;
    int n = n0 + r;
    float2 s1 = ml1[n], s2 = ml2[n];
    float M = fmaxf(s1.x, s2.x);
    float w1 = s1.y * exp2f(s1.x - M), w2 = s2.y * exp2f(s2.x - M);
    float inv = 1.0f / (w1 + w2);
    w1 *= inv;
    w2 *= inv;
    short8 x1 = *(const short8*)(O1 + (size_t)n * CD + p * 8);
    short8 x2 = *(const short8*)(O2 + (size_t)n * CD + p * 8);
    short8 om;
#pragma unroll
    for (int e = 0; e < 8; ++e)
      om[e] = (short)f2bf(w1 * bf2f(x1[e]) + w2 * bf2f(x2[e]));
    *(short8*)(Bls + r * 256 + ((p ^ (r & 7)) * 8)) = om;
  }
  __builtin_amdgcn_s_waitcnt(0);
  __syncthreads();
  f32x16 acc0, acc1;
#pragma unroll
  for (int i = 0; i < 16; ++i) {
    acc0[i] = 0.f;
    acc1[i] = 0.f;
  }
  const int ra = os * 32 + l31;
  const int rb0 = nh * 64 + l31, rb1 = rb0 + 32;
#pragma unroll
  for (int kc = 0; kc < 16; ++kc) {
    short8 a = *(const short8*)(Wls + ra * 256 + (((kc * 2 + l5) ^ (ra & 7)) * 8));
    short8 b0 = *(const short8*)(Bls + rb0 * 256 + (((kc * 2 + l5) ^ (rb0 & 7)) * 8));
    short8 b1 = *(const short8*)(Bls + rb1 * 256 + (((kc * 2 + l5) ^ (rb1 & 7)) * 8));
    acc0 = MFMA32(a, b0, acc0, 0, 0, 0);
    acc1 = MFMA32(a, b1, acc1, 0, 0, 0);
  }
  const int obase = o0 + os * 32;
#pragma unroll
  for (int na = 0; na < 2; ++na) {
    f32x16& acc = na ? acc1 : acc0;
    const int n_g = n0 + nh * 64 + na * 32 + l31;
#pragma unroll
    for (int g = 0; g < 4; ++g) {
      float4 bv = *(const float4*)(out_b + obase + g * 8 + l5 * 4);
      const float* bp = (const float*)&bv;
#pragma unroll
      for (int r = 0; r < 4; ++r) {
        int o = obase + g * 8 + l5 * 4 + r;
        out[((size_t)b * CD + o) * NSEQ + n_g] = acc[g * 4 + r] + bp[r];
      }
    }
  }
}

// ---------------------------------------------------------------------------
extern "C" void kernel_launch(void* const* d_in, const int* in_sizes, int n_in,
                              void* d_out, int out_size, void* d_ws,
                              size_t ws_size, hipStream_t stream) {
  const float* x = (const float*)d_in[0];
  const float* qkv_w = (const float*)d_in[1];
  const float* qkv_b = (const float*)d_in[2];
  const float* out_w = (const float*)d_in[3];
  const float* out_b = (const float*)d_in[4];
  float* out = (float*)d_out;

  const size_t SZ = (size_t)4 * NSEQ * CD;  // elems per (b,4096,256) bf16
  u16* x_t = (u16*)d_ws;
  u16* q_t = x_t + SZ;
  u16* k_t = q_t + SZ;
  u16* v_ = k_t + SZ;
  u16* opart = v_ + SZ;              // 2 key-halves, 2*SZ
  u16* wq = opart + 2 * SZ;          // 768*256
  u16* wo = wq + 768 * CD;           // 256*256
  float2* ml = (float2*)(wo + CD * CD);  // 2*4*4096 float2

  cast_w<<<dim3(768), dim3(256), 0, stream>>>(qkv_w, out_w, wq, wo);
  xpose<<<dim3(64, 4, 4), dim3(256), 0, stream>>>(x, x_t);
  qkv_gemm3<<<dim3(32, 6, 4), dim3(512), 0, stream>>>(wq, qkv_b, x_t, q_t, k_t,
                                                      v_);
  flash6<<<dim3(256), dim3(512), 0, stream>>>(q_t, k_t, v_, opart, ml);
  out_gemm5<<<dim3(32, 2, 4), dim3(512), 0, stream>>>(wo, out_b, opart, ml,
                                                      out);
}

// Round 9
// 230.287 us; speedup vs baseline: 1.0038x; 1.0038x over previous
//
#include <hip/hip_runtime.h>
#include <hip/hip_bf16.h>

typedef unsigned short u16;
typedef unsigned int u32;
typedef __attribute__((ext_vector_type(8))) short short8;   // 8 x bf16 frag
typedef __attribute__((ext_vector_type(4))) short short4v;  // 4 x bf16 pack
typedef __attribute__((ext_vector_type(16))) float f32x16;  // 32x32 acc

#define MFMA32 __builtin_amdgcn_mfma_f32_32x32x16_bf16

#define NSEQ 4096
#define CD 256
// (1/sqrt(256)) * log2(e) = 0.0625 * 1.4426950408889634  -- EXACT.
#define CF 0.09016844005556021f

__device__ __forceinline__ u16 f2bf(float f) {
  u32 u = __float_as_uint(f);
  u += 0x7fffu + ((u >> 16) & 1u);  // RNE
  return (u16)(u >> 16);
}
__device__ __forceinline__ float bf2f(short s) {
  return __uint_as_float(((u32)(u16)s) << 16);
}
// HW packed f32x2 -> bf16x2 (gfx950 v_cvt_pk_bf16_f32), RNE
__device__ __forceinline__ u32 pk2bf(float a, float b) {
  union {
    __hip_bfloat162 h;
    u32 u;
  } cv;
  cv.h = __float22bfloat162_rn(make_float2(a, b));
  return cv.u;
}
// async global -> LDS DMA, 16B per lane; LDS dest = wave-uniform base + lane*16
__device__ __forceinline__ void async16(const void* g, void* l) {
  __builtin_amdgcn_global_load_lds(
      (const __attribute__((address_space(1))) u32*)g,
      (__attribute__((address_space(3))) u32*)l, 16, 0, 0);
}

// ---------------------------------------------------------------------------
// cast weights fp32 -> bf16
// ---------------------------------------------------------------------------
__global__ void cast_w(const float* __restrict__ qkv_w,
                       const float* __restrict__ out_w, u16* __restrict__ wq,
                       u16* __restrict__ wo) {
  int idx = blockIdx.x * 256 + threadIdx.x;
  if (idx < 768 * CD) wq[idx] = f2bf(qkv_w[idx]);
  if (idx < CD * CD) wo[idx] = f2bf(out_w[idx]);
}

// ---------------------------------------------------------------------------
// transpose-cast x: (b, 256, 4096) f32 -> x_t (b, 4096, 256) bf16
// ---------------------------------------------------------------------------
__global__ __launch_bounds__(256) void xpose(const float* __restrict__ x,
                                             u16* __restrict__ x_t) {
  __shared__ float tile[64][65];
  const int t = threadIdx.x;
  const int b = blockIdx.z;
  const int n0 = blockIdx.x * 64, c0 = blockIdx.y * 64;
  const float* xb = x + (size_t)b * CD * NSEQ;
  const int cr = t >> 4, nc4 = (t & 15) * 4;
#pragma unroll
  for (int i = 0; i < 4; ++i) {
    int c = cr + 16 * i;
    float4 v = *(const float4*)(xb + (size_t)(c0 + c) * NSEQ + n0 + nc4);
    tile[c][nc4 + 0] = v.x;
    tile[c][nc4 + 1] = v.y;
    tile[c][nc4 + 2] = v.z;
    tile[c][nc4 + 3] = v.w;
  }
  __syncthreads();
  const int n = t & 63, cc = (t >> 6) * 16;
  u16* dst = x_t + (size_t)b * NSEQ * CD + (size_t)(n0 + n) * CD + c0 + cc;
#pragma unroll
  for (int j = 0; j < 4; ++j) {
    short4v pv;
#pragma unroll
    for (int r = 0; r < 4; ++r) pv[r] = (short)f2bf(tile[cc + 4 * j + r][n]);
    *(short4v*)(dst + 4 * j) = pv;
  }
}

// ---------------------------------------------------------------------------
// QKV projection, 128x128 tile, 512 threads (8 waves), 32x32x16 MFMA.
// Wave w: o-strip (w&3)*32, n-half (w>>2)*64 (2 accs of 32n each).
// grid (32, 6, 4): blockIdx.y in {0,1}=Q {2,3}=K {4,5}=V (128 | 256).
// ---------------------------------------------------------------------------
__global__ __launch_bounds__(512, 1) void qkv_gemm3(
    const u16* __restrict__ wq, const float* __restrict__ qkv_b,
    const u16* __restrict__ x_t, u16* __restrict__ q_t, u16* __restrict__ k_t,
    u16* __restrict__ v_) {
  __shared__ u16 __align__(16) Wls[128 * 256];
  __shared__ u16 __align__(16) Bls[128 * 256];
  const int t = threadIdx.x, w = t >> 6, lane = t & 63;
  const int l31 = lane & 31, l5 = lane >> 5;
  const int os = w & 3, nh = w >> 2;
  const int n0 = blockIdx.x * 128, o0 = blockIdx.y * 128, b = blockIdx.z;
  const u16* Xb = x_t + (size_t)b * NSEQ * CD;
#pragma unroll
  for (int j = 0; j < 8; ++j) {
    int r = w * 16 + j * 2 + l5;
    async16(wq + (size_t)(o0 + r) * CD + ((l31 ^ (r & 7)) * 8),
            Wls + (w * 16 + j * 2) * 256);
    async16(Xb + (size_t)(n0 + r) * CD + ((l31 ^ (r & 7)) * 8),
            Bls + (w * 16 + j * 2) * 256);
  }
  __builtin_amdgcn_s_waitcnt(0);
  __syncthreads();
  f32x16 acc0, acc1;
#pragma unroll
  for (int i = 0; i < 16; ++i) {
    acc0[i] = 0.f;
    acc1[i] = 0.f;
  }
  const int ra = os * 32 + l31;
  const int rb0 = nh * 64 + l31, rb1 = rb0 + 32;
#pragma unroll
  for (int kc = 0; kc < 16; ++kc) {
    short8 a = *(const short8*)(Wls + ra * 256 + (((kc * 2 + l5) ^ (ra & 7)) * 8));
    short8 b0 = *(const short8*)(Bls + rb0 * 256 + (((kc * 2 + l5) ^ (rb0 & 7)) * 8));
    short8 b1 = *(const short8*)(Bls + rb1 * 256 + (((kc * 2 + l5) ^ (rb1 & 7)) * 8));
    acc0 = MFMA32(a, b0, acc0, 0, 0, 0);
    acc1 = MFMA32(a, b1, acc1, 0, 0, 0);
  }
  const int otype = blockIdx.y >> 1;  // 0=Q 1=K 2=V
  const int obase = o0 + os * 32;
#pragma unroll
  for (int na = 0; na < 2; ++na) {
    f32x16& acc = na ? acc1 : acc0;
    const int n_g = n0 + nh * 64 + na * 32 + l31;
    if (otype < 2) {
      u16* dst = (otype == 0 ? q_t : k_t) + (size_t)b * NSEQ * CD +
                 (size_t)n_g * CD + (obase - otype * 256);
#pragma unroll
      for (int g = 0; g < 4; ++g) {
        float4 bv = *(const float4*)(qkv_b + obase + g * 8 + l5 * 4);
        const float* bp = (const float*)&bv;
        short4v pk;
#pragma unroll
        for (int r = 0; r < 4; ++r) pk[r] = (short)f2bf(acc[g * 4 + r] + bp[r]);
        *(short4v*)(dst + g * 8 + l5 * 4) = pk;
      }
    } else {
      u16* dst = v_ + (size_t)b * CD * NSEQ;
#pragma unroll
      for (int g = 0; g < 4; ++g) {
        float4 bv = *(const float4*)(qkv_b + obase + g * 8 + l5 * 4);
        const float* bp = (const float*)&bv;
#pragma unroll
        for (int r = 0; r < 4; ++r) {
          int c = obase - 512 + g * 8 + l5 * 4 + r;
          dst[(size_t)c * NSEQ + n_g] = f2bf(acc[g * 4 + r] + bp[r]);
        }
      }
    }
  }
}

// ---------------------------------------------------------------------------
// Flash attention v7: fully independent per-wave key streams.
// 512 threads (8 waves), m-tile 128, key-split 4 (2 grid halves x 2 wave
// halves), double-buffered K/V DMA (128 KB LDS). ONE barrier per tile.
// Wave (s = w>>1, nh = w&1): m-strip s (32 m), keys = nh 32-row half of each
// 64-key tile -> its OWN online softmax (m,l) stream:
//   S : own 32n x own 32m, K=256 (16 MFMA).
//   softmax: per-lane + 1 shfl_xor(32). No LDS, no barrier, no sharing.
//   P : C/D -> B-operand layout via 4 shfl_xor(32) (R8-verified transform).
//   PV: O[256c x 32m] += V . P over own 32 keys (16 MFMA, 8 accs).
// Emits per-stream normalized O + (m,l); out_gemm6 merges 4 streams.
// ---------------------------------------------------------------------------
__global__ __launch_bounds__(512, 2) void flash7(const u16* __restrict__ q_t,
                                                 const u16* __restrict__ k_t,
                                                 const u16* __restrict__ v_,
                                                 u16* __restrict__ opart,
                                                 float2* __restrict__ ml) {
  __shared__ u16 __align__(16) Kls[2][64 * 256];  // [buf][n][c] swizzled
  __shared__ u16 __align__(16) Vls[2][256 * 64];  // [buf][c][n] swizzled

  const int t = threadIdx.x, w = t >> 6, lane = t & 63;
  const int l31 = lane & 31, l5 = lane >> 5;
  const int s = w >> 1, nh = w & 1;

  // XCD swizzle: each XCD owns one (batch, key-half) -> 4MB K/V in its L2.
  const int linear = blockIdx.x;
  const int xcd = linear & 7, slot = linear >> 3;  // slot in [0,32)
  const int b = xcd >> 1, half = xcd & 1;
  const int m0 = slot * 128;
  const int nbase = half * 2048;
  const int sid = half * 2 + nh;  // merge stream id, 0..3

  const u16* Qb = q_t + (size_t)b * NSEQ * CD;
  const u16* Kb = k_t + (size_t)b * NSEQ * CD;
  const u16* Vb = v_ + (size_t)b * CD * NSEQ;

  const int mrow = m0 + s * 32 + l31;  // global query index

  // Q fragments in registers (B-operand for S), K=256
  short8 qf[16];
#pragma unroll
  for (int kc = 0; kc < 16; ++kc)
    qf[kc] = *(const short8*)(Qb + (size_t)mrow * CD + kc * 16 + l5 * 8);

  const int kr = w * 8;   // K staging rows (2/DMA, 4 DMA)
  const int vrb = w * 32; // V staging rows (8/DMA, 4 DMA)
  const int vr_lane = lane >> 3, vc_lane = lane & 7;

  // stage tile 0 into buf 0
#pragma unroll
  for (int j = 0; j < 4; ++j) {
    int r = kr + j * 2 + l5;
    async16(Kb + (size_t)(nbase + r) * CD + ((l31 ^ (r & 7)) * 8),
            &Kls[0][(kr + j * 2) * 256]);
    int rv = vrb + j * 8 + vr_lane;
    async16(Vb + (size_t)rv * NSEQ + nbase + ((vc_lane ^ (rv & 7)) * 8),
            &Vls[0][(vrb + j * 8) * 64]);
  }

  float mst = -3.0e38f, lst = 0.f;
  f32x16 oa[8];  // O[c = ct*32 + rowmap][m = mrow], own key stream only
#pragma unroll
  for (int i = 0; i < 8; ++i)
#pragma unroll
    for (int r = 0; r < 16; ++r) oa[i][r] = 0.f;

  for (int tt = 0; tt < 32; ++tt) {
    const int cur = tt & 1;
    // drain: tile tt's DMA complete; all waves past their tile tt-1 reads
    __builtin_amdgcn_s_waitcnt(0);
    __syncthreads();
    if (tt + 1 < 32) {
      const int n0 = nbase + (tt + 1) * 64;
      const int nxt = cur ^ 1;
#pragma unroll
      for (int j = 0; j < 4; ++j) {
        int r = kr + j * 2 + l5;
        async16(Kb + (size_t)(n0 + r) * CD + ((l31 ^ (r & 7)) * 8),
                &Kls[nxt][(kr + j * 2) * 256]);
        int rv = vrb + j * 8 + vr_lane;
        async16(Vb + (size_t)rv * NSEQ + n0 + ((vc_lane ^ (rv & 7)) * 8),
                &Vls[nxt][(vrb + j * 8) * 64]);
      }
    }
    // ---- S = K . Q^T : own 32n x own 32m, K=256 ----
    f32x16 sa;
#pragma unroll
    for (int i = 0; i < 16; ++i) sa[i] = 0.f;
    const int rk = nh * 32 + l31;
#pragma unroll
    for (int kc = 0; kc < 16; ++kc) {
      short8 a =
          *(const short8*)(&Kls[cur][rk * 256 + (((kc * 2 + l5) ^ (rk & 7)) * 8)]);
      sa = MFMA32(a, qf[kc], sa, 0, 0, 0);
    }
    // ---- softmax, fully in-wave (m = l31; l5 halves merge via xor32) ----
    float rm = sa[0];
#pragma unroll
    for (int i = 1; i < 16; ++i) rm = fmaxf(rm, sa[i]);
    rm = fmaxf(rm, __shfl_xor(rm, 32));
    float mnew = fmaxf(mst, rm * CF);
    float al = exp2f(mst - mnew);
    mst = mnew;
    // p = exp2(s*CF - mnew) -> packed bf16 dwords d[gg][x]
    // lane holds n_local = 8*gg + 4*l5 + 2x + {0,1} for column m = l31
    u32 d[4][2];
    float ls = 0.f;
#pragma unroll
    for (int gg = 0; gg < 4; ++gg) {
      float p0 = exp2f(sa[gg * 4 + 0] * CF - mnew);
      float p1 = exp2f(sa[gg * 4 + 1] * CF - mnew);
      float p2 = exp2f(sa[gg * 4 + 2] * CF - mnew);
      float p3 = exp2f(sa[gg * 4 + 3] * CF - mnew);
      ls += (p0 + p1) + (p2 + p3);
      d[gg][0] = pk2bf(p0, p1);
      d[gg][1] = pk2bf(p2, p3);
    }
    ls += __shfl_xor(ls, 32);
    lst = lst * al + ls;
    // ---- rescale O only when the running max moved (rare) ----
    if (__ballot(al != 1.0f)) {
#pragma unroll
      for (int i = 0; i < 8; ++i)
#pragma unroll
        for (int r = 0; r < 16; ++r) oa[i][r] *= al;
    }
    // ---- build P B-frags via l5-partner exchange (4 shfl_xor) ----
    // pf[chunk] covers k-slot n_local = chunk*16 + l5*8 + j
    short8 pf[2];
#pragma unroll
    for (int f = 0; f < 2; ++f) {
      const int g0 = f * 2;
      u32 sx0 = l5 ? d[g0][0] : d[g0 + 1][0];
      u32 sx1 = l5 ? d[g0][1] : d[g0 + 1][1];
      u32 e0 = (u32)__shfl_xor((int)sx0, 32);
      u32 e1 = (u32)__shfl_xor((int)sx1, 32);
      union {
        u32 u[4];
        short8 s8;
      } cv;
      cv.u[0] = l5 ? e0 : d[g0][0];
      cv.u[1] = l5 ? e1 : d[g0][1];
      cv.u[2] = l5 ? d[g0 + 1][0] : e0;
      cv.u[3] = l5 ? d[g0 + 1][1] : e1;
      pf[f] = cv.s8;
    }
    // ---- O += V . P : full 256 c (8 subtiles) x own 32 keys ----
#pragma unroll
    for (int f = 0; f < 2; ++f) {
#pragma unroll
      for (int ct = 0; ct < 8; ++ct) {
        int c = ct * 32 + l31;
        short8 vf = *(const short8*)(&Vls[cur][c * 64 +
                                               (((nh * 4 + f * 2 + l5) ^ (c & 7)) * 8)]);
        oa[ct] = MFMA32(vf, pf[f], oa[ct], 0, 0, 0);
      }
    }
  }

  // ---- finalize: per-stream normalized O -> bf16; (m,l) for merge ----
  float inv = 1.0f / lst;
  u16* dst = opart + ((size_t)(sid * 4 + b) * NSEQ + mrow) * CD;
#pragma unroll
  for (int ct = 0; ct < 8; ++ct)
#pragma unroll
    for (int gg = 0; gg < 4; ++gg) {
      short4v pk;
#pragma unroll
      for (int r = 0; r < 4; ++r) pk[r] = (short)f2bf(oa[ct][gg * 4 + r] * inv);
      *(short4v*)(dst + ct * 32 + gg * 8 + l5 * 4) = pk;
    }
  if (lane < 32)
    ml[(size_t)(sid * 4 + b) * NSEQ + mrow] = make_float2(mst, lst);
}

// ---------------------------------------------------------------------------
// out projection + 4-stream split-key merge folded into B-tile staging.
// 128n x 128o tiles, 512 threads. grid (32, 2, 4).
// ---------------------------------------------------------------------------
__global__ __launch_bounds__(512, 1) void out_gemm6(
    const u16* __restrict__ wo, const float* __restrict__ out_b,
    const u16* __restrict__ opart, const float2* __restrict__ ml,
    float* __restrict__ out) {
  __shared__ u16 __align__(16) Wls[128 * 256];
  __shared__ u16 __align__(16) Bls[128 * 256];
  const int t = threadIdx.x, w = t >> 6, lane = t & 63;
  const int l31 = lane & 31, l5 = lane >> 5;
  const int os = w & 3, nh = w >> 2;
  const int n0 = blockIdx.x * 128, o0 = blockIdx.y * 128, b = blockIdx.z;
#pragma unroll
  for (int j = 0; j < 8; ++j) {
    int r = w * 16 + j * 2 + l5;
    async16(wo + (size_t)(o0 + r) * CD + ((l31 ^ (r & 7)) * 8),
            Wls + (w * 16 + j * 2) * 256);
  }
#pragma unroll
  for (int i = 0; i < 8; ++i) {
    int idx = i * 512 + t;
    int r = idx >> 5, p = idx & 31;
    int n = n0 + r;
    float2 st[4];
#pragma unroll
    for (int q = 0; q < 4; ++q) st[q] = ml[(size_t)(q * 4 + b) * NSEQ + n];
    float M = fmaxf(fmaxf(st[0].x, st[1].x), fmaxf(st[2].x, st[3].x));
    float wt[4], tot = 0.f;
#pragma unroll
    for (int q = 0; q < 4; ++q) {
      wt[q] = st[q].y * exp2f(st[q].x - M);
      tot += wt[q];
    }
    float inv = 1.0f / tot;
    float acc[8] = {};
#pragma unroll
    for (int q = 0; q < 4; ++q) {
      float wq_ = wt[q] * inv;
      short8 xq =
          *(const short8*)(opart + ((size_t)(q * 4 + b) * NSEQ + n) * CD + p * 8);
#pragma unroll
      for (int e = 0; e < 8; ++e) acc[e] += wq_ * bf2f(xq[e]);
    }
    short8 om;
#pragma unroll
    for (int e = 0; e < 8; ++e) om[e] = (short)f2bf(acc[e]);
    *(short8*)(Bls + r * 256 + ((p ^ (r & 7)) * 8)) = om;
  }
  __builtin_amdgcn_s_waitcnt(0);
  __syncthreads();
  f32x16 acc0, acc1;
#pragma unroll
  for (int i = 0; i < 16; ++i) {
    acc0[i] = 0.f;
    acc1[i] = 0.f;
  }
  const int ra = os * 32 + l31;
  const int rb0 = nh * 64 + l31, rb1 = rb0 + 32;
#pragma unroll
  for (int kc = 0; kc < 16; ++kc) {
    short8 a = *(const short8*)(Wls + ra * 256 + (((kc * 2 + l5) ^ (ra & 7)) * 8));
    short8 b0 = *(const short8*)(Bls + rb0 * 256 + (((kc * 2 + l5) ^ (rb0 & 7)) * 8));
    short8 b1 = *(const short8*)(Bls + rb1 * 256 + (((kc * 2 + l5) ^ (rb1 & 7)) * 8));
    acc0 = MFMA32(a, b0, acc0, 0, 0, 0);
    acc1 = MFMA32(a, b1, acc1, 0, 0, 0);
  }
  const int obase = o0 + os * 32;
#pragma unroll
  for (int na = 0; na < 2; ++na) {
    f32x16& acc = na ? acc1 : acc0;
    const int n_g = n0 + nh * 64 + na * 32 + l31;
#pragma unroll
    for (int g = 0; g < 4; ++g) {
      float4 bv = *(const float4*)(out_b + obase + g * 8 + l5 * 4);
      const float* bp = (const float*)&bv;
#pragma unroll
      for (int r = 0; r < 4; ++r) {
        int o = obase + g * 8 + l5 * 4 + r;
        out[((size_t)b * CD + o) * NSEQ + n_g] = acc[g * 4 + r] + bp[r];
      }
    }
  }
}

// ---------------------------------------------------------------------------
extern "C" void kernel_launch(void* const* d_in, const int* in_sizes, int n_in,
                              void* d_out, int out_size, void* d_ws,
                              size_t ws_size, hipStream_t stream) {
  const float* x = (const float*)d_in[0];
  const float* qkv_w = (const float*)d_in[1];
  const float* qkv_b = (const float*)d_in[2];
  const float* out_w = (const float*)d_in[3];
  const float* out_b = (const float*)d_in[4];
  float* out = (float*)d_out;

  const size_t SZ = (size_t)4 * NSEQ * CD;  // elems per (b,4096,256) bf16
  u16* x_t = (u16*)d_ws;
  u16* q_t = x_t + SZ;
  u16* k_t = q_t + SZ;
  u16* v_ = k_t + SZ;
  u16* opart = v_ + SZ;              // 4 key-stream quarters, 4*SZ
  u16* wq = opart + 4 * SZ;          // 768*256
  u16* wo = wq + 768 * CD;           // 256*256
  float2* ml = (float2*)(wo + CD * CD);  // 4*4*4096 float2

  cast_w<<<dim3(768), dim3(256), 0, stream>>>(qkv_w, out_w, wq, wo);
  xpose<<<dim3(64, 4, 4), dim3(256), 0, stream>>>(x, x_t);
  qkv_gemm3<<<dim3(32, 6, 4), dim3(512), 0, stream>>>(wq, qkv_b, x_t, q_t, k_t,
                                                      v_);
  flash7<<<dim3(256), dim3(512), 0, stream>>>(q_t, k_t, v_, opart, ml);
  out_gemm6<<<dim3(32, 2, 4), dim3(512), 0, stream>>>(wo, out_b, opart, ml,
                                                      out);
}

// Round 10
// 206.390 us; speedup vs baseline: 1.1200x; 1.1158x over previous
//
#include <hip/hip_runtime.h>
#include <hip/hip_bf16.h>

typedef unsigned short u16;
typedef unsigned int u32;
typedef __attribute__((ext_vector_type(8))) short short8;   // 8 x bf16 frag
typedef __attribute__((ext_vector_type(4))) short short4v;  // 4 x bf16 pack
typedef __attribute__((ext_vector_type(16))) float f32x16;  // 32x32 acc

#define MFMA32 __builtin_amdgcn_mfma_f32_32x32x16_bf16

#define NSEQ 4096
#define CD 256
// (1/sqrt(256)) * log2(e) = 0.0625 * 1.4426950408889634  -- EXACT.
#define CF 0.09016844005556021f

__device__ __forceinline__ u16 f2bf(float f) {
  u32 u = __float_as_uint(f);
  u += 0x7fffu + ((u >> 16) & 1u);  // RNE
  return (u16)(u >> 16);
}
__device__ __forceinline__ float bf2f(short s) {
  return __uint_as_float(((u32)(u16)s) << 16);
}
// HW packed f32x2 -> bf16x2 (gfx950 v_cvt_pk_bf16_f32), RNE
__device__ __forceinline__ u32 pk2bf(float a, float b) {
  union {
    __hip_bfloat162 h;
    u32 u;
  } cv;
  cv.h = __float22bfloat162_rn(make_float2(a, b));
  return cv.u;
}
// async global -> LDS DMA, 16B per lane; LDS dest = wave-uniform base + lane*16
__device__ __forceinline__ void async16(const void* g, void* l) {
  __builtin_amdgcn_global_load_lds(
      (const __attribute__((address_space(1))) u32*)g,
      (__attribute__((address_space(3))) u32*)l, 16, 0, 0);
}

// ---------------------------------------------------------------------------
// transpose-cast x: (b, 256, 4096) f32 -> x_t (b, 4096, 256) bf16
// + folded weight cast (1024 blocks x 256 weight elems = exactly 768*256+256*256)
// ---------------------------------------------------------------------------
__global__ __launch_bounds__(256) void xpose_cast(const float* __restrict__ x,
                                                  u16* __restrict__ x_t,
                                                  const float* __restrict__ qkv_w,
                                                  const float* __restrict__ out_w,
                                                  u16* __restrict__ wq,
                                                  u16* __restrict__ wo) {
  __shared__ float tile[64][65];
  const int t = threadIdx.x;
  // ---- weight cast slice ----
  {
    int lin = blockIdx.x + 64 * (blockIdx.y + 4 * blockIdx.z);
    int widx = lin * 256 + t;
    if (widx < 768 * CD)
      wq[widx] = f2bf(qkv_w[widx]);
    else
      wo[widx - 768 * CD] = f2bf(out_w[widx - 768 * CD]);
  }
  // ---- transpose-cast ----
  const int b = blockIdx.z;
  const int n0 = blockIdx.x * 64, c0 = blockIdx.y * 64;
  const float* xb = x + (size_t)b * CD * NSEQ;
  const int cr = t >> 4, nc4 = (t & 15) * 4;
#pragma unroll
  for (int i = 0; i < 4; ++i) {
    int c = cr + 16 * i;
    float4 v = *(const float4*)(xb + (size_t)(c0 + c) * NSEQ + n0 + nc4);
    tile[c][nc4 + 0] = v.x;
    tile[c][nc4 + 1] = v.y;
    tile[c][nc4 + 2] = v.z;
    tile[c][nc4 + 3] = v.w;
  }
  __syncthreads();
  const int n = t & 63, cc = (t >> 6) * 16;
  u16* dst = x_t + (size_t)b * NSEQ * CD + (size_t)(n0 + n) * CD + c0 + cc;
#pragma unroll
  for (int j = 0; j < 4; ++j) {
    short4v pv;
#pragma unroll
    for (int r = 0; r < 4; ++r) pv[r] = (short)f2bf(tile[cc + 4 * j + r][n]);
    *(short4v*)(dst + 4 * j) = pv;
  }
}

// ---------------------------------------------------------------------------
// QKV projection, 128x128 tile, 512 threads (8 waves), 32x32x16 MFMA.
// (unchanged from R9)
// ---------------------------------------------------------------------------
__global__ __launch_bounds__(512, 1) void qkv_gemm3(
    const u16* __restrict__ wq, const float* __restrict__ qkv_b,
    const u16* __restrict__ x_t, u16* __restrict__ q_t, u16* __restrict__ k_t,
    u16* __restrict__ v_) {
  __shared__ u16 __align__(16) Wls[128 * 256];
  __shared__ u16 __align__(16) Bls[128 * 256];
  const int t = threadIdx.x, w = t >> 6, lane = t & 63;
  const int l31 = lane & 31, l5 = lane >> 5;
  const int os = w & 3, nh = w >> 2;
  const int n0 = blockIdx.x * 128, o0 = blockIdx.y * 128, b = blockIdx.z;
  const u16* Xb = x_t + (size_t)b * NSEQ * CD;
#pragma unroll
  for (int j = 0; j < 8; ++j) {
    int r = w * 16 + j * 2 + l5;
    async16(wq + (size_t)(o0 + r) * CD + ((l31 ^ (r & 7)) * 8),
            Wls + (w * 16 + j * 2) * 256);
    async16(Xb + (size_t)(n0 + r) * CD + ((l31 ^ (r & 7)) * 8),
            Bls + (w * 16 + j * 2) * 256);
  }
  __builtin_amdgcn_s_waitcnt(0);
  __syncthreads();
  f32x16 acc0, acc1;
#pragma unroll
  for (int i = 0; i < 16; ++i) {
    acc0[i] = 0.f;
    acc1[i] = 0.f;
  }
  const int ra = os * 32 + l31;
  const int rb0 = nh * 64 + l31, rb1 = rb0 + 32;
#pragma unroll
  for (int kc = 0; kc < 16; ++kc) {
    short8 a = *(const short8*)(Wls + ra * 256 + (((kc * 2 + l5) ^ (ra & 7)) * 8));
    short8 b0 = *(const short8*)(Bls + rb0 * 256 + (((kc * 2 + l5) ^ (rb0 & 7)) * 8));
    short8 b1 = *(const short8*)(Bls + rb1 * 256 + (((kc * 2 + l5) ^ (rb1 & 7)) * 8));
    acc0 = MFMA32(a, b0, acc0, 0, 0, 0);
    acc1 = MFMA32(a, b1, acc1, 0, 0, 0);
  }
  const int otype = blockIdx.y >> 1;  // 0=Q 1=K 2=V
  const int obase = o0 + os * 32;
#pragma unroll
  for (int na = 0; na < 2; ++na) {
    f32x16& acc = na ? acc1 : acc0;
    const int n_g = n0 + nh * 64 + na * 32 + l31;
    if (otype < 2) {
      u16* dst = (otype == 0 ? q_t : k_t) + (size_t)b * NSEQ * CD +
                 (size_t)n_g * CD + (obase - otype * 256);
#pragma unroll
      for (int g = 0; g < 4; ++g) {
        float4 bv = *(const float4*)(qkv_b + obase + g * 8 + l5 * 4);
        const float* bp = (const float*)&bv;
        short4v pk;
#pragma unroll
        for (int r = 0; r < 4; ++r) pk[r] = (short)f2bf(acc[g * 4 + r] + bp[r]);
        *(short4v*)(dst + g * 8 + l5 * 4) = pk;
      }
    } else {
      u16* dst = v_ + (size_t)b * CD * NSEQ;
#pragma unroll
      for (int g = 0; g < 4; ++g) {
        float4 bv = *(const float4*)(qkv_b + obase + g * 8 + l5 * 4);
        const float* bp = (const float*)&bv;
#pragma unroll
        for (int r = 0; r < 4; ++r) {
          int c = obase - 512 + g * 8 + l5 * 4 + r;
          dst[(size_t)c * NSEQ + n_g] = f2bf(acc[g * 4 + r] + bp[r]);
        }
      }
    }
  }
}

// ---------------------------------------------------------------------------
// Flash attention v8: de-phase-locked. 256-thread blocks (4 waves), 32-key
// tiles, K+V double-buffered (48 KB LDS) -> TWO blocks per CU with
// INDEPENDENT barrier domains. Key-split 4 (grid 512 = 4b x 4q x 32 mblk).
// Wave w = m-strip (32 m of the 128-m tile), owns ALL 32 keys of each tile ->
// fully independent online-softmax stream per (m, quarter) (flash7 math).
//   S : 32n x 32m, K=256 (16 MFMA, 16 K-frag LDS reads).
//   softmax: per-lane + 1 shfl_xor(32). P: 4 shfl_xor transform (verified).
//   PV: O[256c x 32m] (16 MFMA, 16 V-frag LDS reads).
// V staged in PAIRED c-rows (rows of 128 B) to keep 4-way-floor bank behavior.
// ---------------------------------------------------------------------------
__global__ __launch_bounds__(256, 2) void flash8(const u16* __restrict__ q_t,
                                                 const u16* __restrict__ k_t,
                                                 const u16* __restrict__ v_,
                                                 u16* __restrict__ opart,
                                                 float2* __restrict__ ml) {
  __shared__ u16 __align__(16) Kls[2][32 * 256];  // [buf][n][c] swizzled
  __shared__ u16 __align__(16) Vls[2][128 * 64];  // [buf][c-pair rows]

  const int t = threadIdx.x, w = t >> 6, lane = t & 63;
  const int l31 = lane & 31, l5 = lane >> 5;

  // XCD swizzle: xcd owns (b, quarter-pair) -> K/V/Q working set ~4MB in L2.
  const int linear = blockIdx.x;
  const int xcd = linear & 7, slot = linear >> 3;  // slot in [0,64)
  const int b = xcd >> 1;
  const int q = (xcd & 1) * 2 + (slot >> 5);  // key-quarter 0..3
  const int mblk = slot & 31;
  const int m0 = mblk * 128;
  const int nbase = q * 1024;

  const u16* Qb = q_t + (size_t)b * NSEQ * CD;
  const u16* Kb = k_t + (size_t)b * NSEQ * CD;
  const u16* Vb = v_ + (size_t)b * CD * NSEQ;

  const int mrow = m0 + w * 32 + l31;  // global query index

  // Q fragments in registers (B-operand for S), K=256
  short8 qf[16];
#pragma unroll
  for (int kc = 0; kc < 16; ++kc)
    qf[kc] = *(const short8*)(Qb + (size_t)mrow * CD + kc * 16 + l5 * 8);

  // --- per-lane staging address constants ---
  // K: wave w stages rows w*8 + j*2 + l5 (2 rows per 1KB DMA, 4 DMAs)
  // V: paired-row layout: LDS row c2 (128 B) holds c = 2*c2 + (ch>>2),
  //    n-span (ch&3)*8..+8, phys chunk = ch ^ (c2&7). DMA lane covers
  //    row c2 = w*32 + j*8 + (lane>>3), phys chunk lane&7.
  int krow[4];
  const u16* ksrc[4];
#pragma unroll
  for (int j = 0; j < 4; ++j) {
    krow[j] = w * 8 + j * 2 + l5;
    ksrc[j] = Kb + (size_t)krow[j] * CD + ((l31 ^ (krow[j] & 7)) * 8);
  }
  const u16* vsrc[4];
#pragma unroll
  for (int j = 0; j < 4; ++j) {
    int c2 = w * 32 + j * 8 + (lane >> 3);
    int chl = (lane & 7) ^ (c2 & 7);
    int c = (c2 << 1) | (chl >> 2);
    vsrc[j] = Vb + (size_t)c * NSEQ + (chl & 3) * 8;
  }

  // stage tile 0 into buf 0
#pragma unroll
  for (int j = 0; j < 4; ++j) {
    async16(ksrc[j] + (size_t)nbase * CD, &Kls[0][(w * 8 + j * 2) * 256]);
    async16(vsrc[j] + nbase, &Vls[0][(w * 32 + j * 8) * 64]);
  }

  float mst = -3.0e38f, lst = 0.f;
  f32x16 oa[8];  // O[c = ct*32 + rowmap][m = mrow]
#pragma unroll
  for (int i = 0; i < 8; ++i)
#pragma unroll
    for (int r = 0; r < 16; ++r) oa[i][r] = 0.f;

  for (int tt = 0; tt < 32; ++tt) {
    const int cur = tt & 1;
    // drain: tile tt's DMA complete; prior reads of buf[cur] done
    __builtin_amdgcn_s_waitcnt(0);
    __syncthreads();
    if (tt + 1 < 32) {
      const int n0 = nbase + (tt + 1) * 32;
      const int nxt = cur ^ 1;
#pragma unroll
      for (int j = 0; j < 4; ++j) {
        async16(ksrc[j] + (size_t)n0 * CD, &Kls[nxt][(w * 8 + j * 2) * 256]);
        async16(vsrc[j] + n0, &Vls[nxt][(w * 32 + j * 8) * 64]);
      }
    }
    // ---- S = K . Q^T : 32n x own 32m, K=256 ----
    f32x16 sa;
#pragma unroll
    for (int i = 0; i < 16; ++i) sa[i] = 0.f;
#pragma unroll
    for (int kc = 0; kc < 16; ++kc) {
      short8 a =
          *(const short8*)(&Kls[cur][l31 * 256 + (((kc * 2 + l5) ^ (l31 & 7)) * 8)]);
      sa = MFMA32(a, qf[kc], sa, 0, 0, 0);
    }
    // ---- softmax, fully in-wave (m = l31; l5 halves merge via xor32) ----
    float rm = sa[0];
#pragma unroll
    for (int i = 1; i < 16; ++i) rm = fmaxf(rm, sa[i]);
    rm = fmaxf(rm, __shfl_xor(rm, 32));
    float mnew = fmaxf(mst, rm * CF);
    float al = exp2f(mst - mnew);
    mst = mnew;
    // p -> packed bf16 dwords; lane holds n = 8*gg + 4*l5 + 2x + {0,1}
    u32 d[4][2];
    float ls = 0.f;
#pragma unroll
    for (int gg = 0; gg < 4; ++gg) {
      float p0 = exp2f(sa[gg * 4 + 0] * CF - mnew);
      float p1 = exp2f(sa[gg * 4 + 1] * CF - mnew);
      float p2 = exp2f(sa[gg * 4 + 2] * CF - mnew);
      float p3 = exp2f(sa[gg * 4 + 3] * CF - mnew);
      ls += (p0 + p1) + (p2 + p3);
      d[gg][0] = pk2bf(p0, p1);
      d[gg][1] = pk2bf(p2, p3);
    }
    ls += __shfl_xor(ls, 32);
    lst = lst * al + ls;
    // ---- rescale O only when the running max moved (rare) ----
    if (__ballot(al != 1.0f)) {
#pragma unroll
      for (int i = 0; i < 8; ++i)
#pragma unroll
        for (int r = 0; r < 16; ++r) oa[i][r] *= al;
    }
    // ---- build P B-frags via l5-partner exchange (4 shfl_xor) ----
    short8 pf[2];
#pragma unroll
    for (int f = 0; f < 2; ++f) {
      const int g0 = f * 2;
      u32 sx0 = l5 ? d[g0][0] : d[g0 + 1][0];
      u32 sx1 = l5 ? d[g0][1] : d[g0 + 1][1];
      u32 e0 = (u32)__shfl_xor((int)sx0, 32);
      u32 e1 = (u32)__shfl_xor((int)sx1, 32);
      union {
        u32 u[4];
        short8 s8;
      } cv;
      cv.u[0] = l5 ? e0 : d[g0][0];
      cv.u[1] = l5 ? e1 : d[g0][1];
      cv.u[2] = l5 ? d[g0 + 1][0] : e0;
      cv.u[3] = l5 ? d[g0 + 1][1] : e1;
      pf[f] = cv.s8;
    }
    // ---- O += V . P : full 256 c (8 subtiles) x 32 keys ----
#pragma unroll
    for (int f = 0; f < 2; ++f) {
#pragma unroll
      for (int ct = 0; ct < 8; ++ct) {
        // paired-row V read: c = ct*32+l31 -> row c2 = ct*16+(l31>>1),
        // logical chunk = (c&1)*4 + f*2 + l5, phys = chunk ^ (c2&7)
        int c2r = ct * 16 + (l31 >> 1);
        int chl = ((l31 & 1) << 2) | (f * 2 + l5);
        short8 vf =
            *(const short8*)(&Vls[cur][c2r * 64 + ((chl ^ (c2r & 7)) * 8)]);
        oa[ct] = MFMA32(vf, pf[f], oa[ct], 0, 0, 0);
      }
    }
  }

  // ---- finalize: per-stream normalized O -> bf16; (m,l) for merge ----
  float inv = 1.0f / lst;
  u16* dst = opart + ((size_t)(q * 4 + b) * NSEQ + mrow) * CD;
#pragma unroll
  for (int ct = 0; ct < 8; ++ct)
#pragma unroll
    for (int gg = 0; gg < 4; ++gg) {
      short4v pk;
#pragma unroll
      for (int r = 0; r < 4; ++r) pk[r] = (short)f2bf(oa[ct][gg * 4 + r] * inv);
      *(short4v*)(dst + ct * 32 + gg * 8 + l5 * 4) = pk;
    }
  if (lane < 32)
    ml[(size_t)(q * 4 + b) * NSEQ + mrow] = make_float2(mst, lst);
}

// ---------------------------------------------------------------------------
// out projection + 4-stream split-key merge folded into B-tile staging.
// (unchanged from R9)
// ---------------------------------------------------------------------------
__global__ __launch_bounds__(512, 1) void out_gemm6(
    const u16* __restrict__ wo, const float* __restrict__ out_b,
    const u16* __restrict__ opart, const float2* __restrict__ ml,
    float* __restrict__ out) {
  __shared__ u16 __align__(16) Wls[128 * 256];
  __shared__ u16 __align__(16) Bls[128 * 256];
  const int t = threadIdx.x, w = t >> 6, lane = t & 63;
  const int l31 = lane & 31, l5 = lane >> 5;
  const int os = w & 3, nh = w >> 2;
  const int n0 = blockIdx.x * 128, o0 = blockIdx.y * 128, b = blockIdx.z;
#pragma unroll
  for (int j = 0; j < 8; ++j) {
    int r = w * 16 + j * 2 + l5;
    async16(wo + (size_t)(o0 + r) * CD + ((l31 ^ (r & 7)) * 8),
            Wls + (w * 16 + j * 2) * 256);
  }
#pragma unroll
  for (int i = 0; i < 8; ++i) {
    int idx = i * 512 + t;
    int r = idx >> 5, p = idx & 31;
    int n = n0 + r;
    float2 st[4];
#pragma unroll
    for (int qq = 0; qq < 4; ++qq) st[qq] = ml[(size_t)(qq * 4 + b) * NSEQ + n];
    float M = fmaxf(fmaxf(st[0].x, st[1].x), fmaxf(st[2].x, st[3].x));
    float wt[4], tot = 0.f;
#pragma unroll
    for (int qq = 0; qq < 4; ++qq) {
      wt[qq] = st[qq].y * exp2f(st[qq].x - M);
      tot += wt[qq];
    }
    float inv = 1.0f / tot;
    float acc[8] = {};
#pragma unroll
    for (int qq = 0; qq < 4; ++qq) {
      float wq_ = wt[qq] * inv;
      short8 xq =
          *(const short8*)(opart + ((size_t)(qq * 4 + b) * NSEQ + n) * CD + p * 8);
#pragma unroll
      for (int e = 0; e < 8; ++e) acc[e] += wq_ * bf2f(xq[e]);
    }
    short8 om;
#pragma unroll
    for (int e = 0; e < 8; ++e) om[e] = (short)f2bf(acc[e]);
    *(short8*)(Bls + r * 256 + ((p ^ (r & 7)) * 8)) = om;
  }
  __builtin_amdgcn_s_waitcnt(0);
  __syncthreads();
  f32x16 acc0, acc1;
#pragma unroll
  for (int i = 0; i < 16; ++i) {
    acc0[i] = 0.f;
    acc1[i] = 0.f;
  }
  const int ra = os * 32 + l31;
  const int rb0 = nh * 64 + l31, rb1 = rb0 + 32;
#pragma unroll
  for (int kc = 0; kc < 16; ++kc) {
    short8 a = *(const short8*)(Wls + ra * 256 + (((kc * 2 + l5) ^ (ra & 7)) * 8));
    short8 b0 = *(const short8*)(Bls + rb0 * 256 + (((kc * 2 + l5) ^ (rb0 & 7)) * 8));
    short8 b1 = *(const short8*)(Bls + rb1 * 256 + (((kc * 2 + l5) ^ (rb1 & 7)) * 8));
    acc0 = MFMA32(a, b0, acc0, 0, 0, 0);
    acc1 = MFMA32(a, b1, acc1, 0, 0, 0);
  }
  const int obase = o0 + os * 32;
#pragma unroll
  for (int na = 0; na < 2; ++na) {
    f32x16& acc = na ? acc1 : acc0;
    const int n_g = n0 + nh * 64 + na * 32 + l31;
#pragma unroll
    for (int g = 0; g < 4; ++g) {
      float4 bv = *(const float4*)(out_b + obase + g * 8 + l5 * 4);
      const float* bp = (const float*)&bv;
#pragma unroll
      for (int r = 0; r < 4; ++r) {
        int o = obase + g * 8 + l5 * 4 + r;
        out[((size_t)b * CD + o) * NSEQ + n_g] = acc[g * 4 + r] + bp[r];
      }
    }
  }
}

// ---------------------------------------------------------------------------
extern "C" void kernel_launch(void* const* d_in, const int* in_sizes, int n_in,
                              void* d_out, int out_size, void* d_ws,
                              size_t ws_size, hipStream_t stream) {
  const float* x = (const float*)d_in[0];
  const float* qkv_w = (const float*)d_in[1];
  const float* qkv_b = (const float*)d_in[2];
  const float* out_w = (const float*)d_in[3];
  const float* out_b = (const float*)d_in[4];
  float* out = (float*)d_out;

  const size_t SZ = (size_t)4 * NSEQ * CD;  // elems per (b,4096,256) bf16
  u16* x_t = (u16*)d_ws;
  u16* q_t = x_t + SZ;
  u16* k_t = q_t + SZ;
  u16* v_ = k_t + SZ;
  u16* opart = v_ + SZ;              // 4 key-stream quarters, 4*SZ
  u16* wq = opart + 4 * SZ;          // 768*256
  u16* wo = wq + 768 * CD;           // 256*256
  float2* ml = (float2*)(wo + CD * CD);  // 4*4*4096 float2

  xpose_cast<<<dim3(64, 4, 4), dim3(256), 0, stream>>>(x, x_t, qkv_w, out_w,
                                                       wq, wo);
  qkv_gemm3<<<dim3(32, 6, 4), dim3(512), 0, stream>>>(wq, qkv_b, x_t, q_t, k_t,
                                                      v_);
  flash8<<<dim3(512), dim3(256), 0, stream>>>(q_t, k_t, v_, opart, ml);
  out_gemm6<<<dim3(32, 2, 4), dim3(512), 0, stream>>>(wo, out_b, opart, ml,
                                                      out);
}